// Round 1
// baseline (415.898 us; speedup 1.0000x reference)
//
#include <hip/hip_runtime.h>
#include <math.h>

// Problem constants (reference: B,N,T,F_IN,F_OUT = 32,512,12,64,64)
#define BB 32
#define NN 512
#define TT 12
#define FF 64
#define ROWS 64   // n-rows per workgroup
#define MT 64     // m-tile size
#define LDF 68    // padded leading dim (stride ≡ 4 mod 32 banks)
#define NTILES (NN / MT)

typedef float v4 __attribute__((ext_vector_type(4)));

__global__ __launch_bounds__(256)
void sgcn_fused(const float* __restrict__ x,
                const float* __restrict__ adj,
                const float* __restrict__ W,
                float* __restrict__ out)
{
    __shared__ float sXn[ROWS][LDF];  // query rows
    __shared__ float sXm[MT][LDF];    // key/value tile; reused as A in epilogue
    __shared__ float sP [ROWS][LDF];  // logits -> masked probs; reused as W in epilogue
    __shared__ float sFac[ROWS];
    __shared__ float sL  [ROWS];

    const int wg = blockIdx.x;
    const int nb = wg & 7;            // N/ROWS = 8
    const int bt = wg >> 3;
    const int t  = bt % TT;
    const int b  = bt / TT;
    const int n0 = nb * ROWS;

    const int tid = threadIdx.x;
    const int ti  = tid & 15;         // output rows: ti + 16*r
    const int tj  = tid >> 4;         // output cols: tj*4 + c

    // ---- stage Xn (64 rows x 64 f) ----
    #pragma unroll
    for (int k = 0; k < 4; ++k) {
        int idx = tid + k * 256;
        int row = idx >> 4;
        int c4  = (idx & 15) << 2;
        const float* src = x + (((b * NN + n0 + row) * TT + t) * FF) + c4;
        *(v4*)&sXn[row][c4] = *(const v4*)src;
    }

    float agg[4][4];
    #pragma unroll
    for (int r = 0; r < 4; ++r)
        #pragma unroll
        for (int c = 0; c < 4; ++c) agg[r][c] = 0.f;

    // online-softmax state (held by softmax-mapped threads: 4 lanes per row)
    float m_run = -INFINITY, l_run = 0.f;
    const int rr = tid >> 2;          // row 0..63
    const int qq = tid & 3;           // 16-col chunk within row
    const float* adjrow = adj + (size_t)(n0 + rr) * NN;

    for (int mt = 0; mt < NTILES; ++mt) {
        const int m0 = mt * MT;
        __syncthreads();              // prev GEMM2 done with sXm/sP

        // ---- stage Xm tile ----
        #pragma unroll
        for (int k = 0; k < 4; ++k) {
            int idx = tid + k * 256;
            int row = idx >> 4;
            int c4  = (idx & 15) << 2;
            const float* src = x + (((b * NN + m0 + row) * TT + t) * FF) + c4;
            *(v4*)&sXm[row][c4] = *(const v4*)src;
        }
        __syncthreads();

        // ---- GEMM1: S = Xn * Xm^T (scaled), 4x4 per thread ----
        float acc[4][4];
        #pragma unroll
        for (int r = 0; r < 4; ++r)
            #pragma unroll
            for (int c = 0; c < 4; ++c) acc[r][c] = 0.f;

        #pragma unroll
        for (int f4 = 0; f4 < 16; ++f4) {
            v4 a[4], bv[4];
            #pragma unroll
            for (int r = 0; r < 4; ++r) a[r]  = *(const v4*)&sXn[ti + 16*r][f4*4];
            #pragma unroll
            for (int c = 0; c < 4; ++c) bv[c] = *(const v4*)&sXm[tj*4 + c][f4*4];
            #pragma unroll
            for (int r = 0; r < 4; ++r)
                #pragma unroll
                for (int c = 0; c < 4; ++c)
                    #pragma unroll
                    for (int k = 0; k < 4; ++k)
                        acc[r][c] += a[r][k] * bv[c][k];
        }
        // write scaled logits to sP
        #pragma unroll
        for (int r = 0; r < 4; ++r) {
            v4 v;
            #pragma unroll
            for (int c = 0; c < 4; ++c) v[c] = acc[r][c] * 0.125f;
            *(v4*)&sP[ti + 16*r][tj*4] = v;
        }
        __syncthreads();

        // ---- online softmax over this tile (4 threads per row, 16 cols each) ----
        v4 sv[4];
        float mx = -INFINITY;
        #pragma unroll
        for (int k4 = 0; k4 < 4; ++k4) {
            sv[k4] = *(const v4*)&sP[rr][qq*16 + k4*4];
            mx = fmaxf(mx, fmaxf(fmaxf(sv[k4][0], sv[k4][1]), fmaxf(sv[k4][2], sv[k4][3])));
        }
        mx = fmaxf(mx, __shfl_xor(mx, 1));
        mx = fmaxf(mx, __shfl_xor(mx, 2));
        const float m_new = fmaxf(m_run, mx);
        const float fac   = __expf(m_run - m_new);   // 0 on first tile (-inf)
        float lsum = 0.f;
        #pragma unroll
        for (int k4 = 0; k4 < 4; ++k4) {
            v4 av = *(const v4*)(adjrow + m0 + qq*16 + k4*4);
            v4 p;
            #pragma unroll
            for (int k = 0; k < 4; ++k) p[k] = __expf(sv[k4][k] - m_new);
            lsum += (p[0] + p[1]) + (p[2] + p[3]);   // denom WITHOUT adj (post-softmax mask)
            #pragma unroll
            for (int k = 0; k < 4; ++k) p[k] *= av[k];
            *(v4*)&sP[rr][qq*16 + k4*4] = p;
        }
        lsum += __shfl_xor(lsum, 1);
        lsum += __shfl_xor(lsum, 2);
        l_run = l_run * fac + lsum;
        m_run = m_new;
        if (qq == 0) sFac[rr] = fac;
        __syncthreads();

        // ---- rescale agg, GEMM2: agg += (adj .* P) * Xm ----
        float facr[4];
        #pragma unroll
        for (int r = 0; r < 4; ++r) facr[r] = sFac[ti + 16*r];
        #pragma unroll
        for (int r = 0; r < 4; ++r)
            #pragma unroll
            for (int c = 0; c < 4; ++c) agg[r][c] *= facr[r];

        #pragma unroll
        for (int m4 = 0; m4 < 16; ++m4) {
            v4 a[4], bv[4];
            #pragma unroll
            for (int r = 0; r < 4; ++r) a[r]  = *(const v4*)&sP[ti + 16*r][m4*4];
            #pragma unroll
            for (int k = 0; k < 4; ++k) bv[k] = *(const v4*)&sXm[m4*4 + k][tj*4];
            #pragma unroll
            for (int r = 0; r < 4; ++r)
                #pragma unroll
                for (int c = 0; c < 4; ++c)
                    #pragma unroll
                    for (int k = 0; k < 4; ++k)
                        agg[r][c] += a[r][k] * bv[k][c];
        }
    }

    // ---- epilogue: normalize, A*W^T, relu, strided store ----
    if (qq == 0) sL[rr] = l_run;
    __syncthreads();                  // also: all GEMM2 reads of sXm/sP done

    float invl[4];
    #pragma unroll
    for (int r = 0; r < 4; ++r) invl[r] = 0.125f / sL[ti + 16*r];
    #pragma unroll
    for (int r = 0; r < 4; ++r) {
        v4 v;
        #pragma unroll
        for (int c = 0; c < 4; ++c) v[c] = agg[r][c] * invl[r];
        *(v4*)&sXm[ti + 16*r][tj*4] = v;   // A lives in sXm now
    }
    // stage W (64x64) into sP
    #pragma unroll
    for (int k = 0; k < 4; ++k) {
        int idx = tid + k * 256;
        int row = idx >> 4;
        int c4  = (idx & 15) << 2;
        *(v4*)&sP[row][c4] = *(const v4*)(W + row * FF + c4);
    }
    __syncthreads();

    float oacc[4][4];
    #pragma unroll
    for (int r = 0; r < 4; ++r)
        #pragma unroll
        for (int c = 0; c < 4; ++c) oacc[r][c] = 0.f;

    #pragma unroll
    for (int f4 = 0; f4 < 16; ++f4) {
        v4 a[4], bv[4];
        #pragma unroll
        for (int r = 0; r < 4; ++r) a[r]  = *(const v4*)&sXm[ti + 16*r][f4*4];
        #pragma unroll
        for (int c = 0; c < 4; ++c) bv[c] = *(const v4*)&sP[tj*4 + c][f4*4];
        #pragma unroll
        for (int r = 0; r < 4; ++r)
            #pragma unroll
            for (int c = 0; c < 4; ++c)
                #pragma unroll
                for (int k = 0; k < 4; ++k)
                    oacc[r][c] += a[r][k] * bv[c][k];
    }

    #pragma unroll
    for (int r = 0; r < 4; ++r) {
        float* dst = out + (((b * NN + n0 + ti + 16*r) * TT + t) * FF) + tj*4;
        v4 v;
        #pragma unroll
        for (int c = 0; c < 4; ++c) v[c] = fmaxf(oacc[r][c], 0.f);
        *(v4*)dst = v;
    }
}

extern "C" void kernel_launch(void* const* d_in, const int* in_sizes, int n_in,
                              void* d_out, int out_size, void* d_ws, size_t ws_size,
                              hipStream_t stream) {
    const float* x   = (const float*)d_in[0];
    const float* adj = (const float*)d_in[1];
    const float* W   = (const float*)d_in[2];
    float* out = (float*)d_out;

    dim3 grid(BB * TT * (NN / ROWS));   // 32*12*8 = 3072 workgroups
    sgcn_fused<<<grid, dim3(256), 0, stream>>>(x, adj, W, out);
}

// Round 2
// 277.827 us; speedup vs baseline: 1.4970x; 1.4970x over previous
//
#include <hip/hip_runtime.h>
#include <math.h>

// B,N,T,F = 32,512,12,64
#define BB 32
#define NN 512
#define TT 12
#define FF 64
#define ROWS 64            // query rows per WG
#define MT 64              // key tile
#define NTILES (NN / MT)
#define LDH 72             // LDS stride in halves (144 B: 16B-aligned, 2-way banks)

typedef float  f32x4   __attribute__((ext_vector_type(4)));
typedef float  v4f     __attribute__((ext_vector_type(4)));
typedef short  short8v __attribute__((ext_vector_type(8)));
typedef short  short4v __attribute__((ext_vector_type(4)));

static __device__ __forceinline__ short f2bf(float f) {
    unsigned u = __builtin_bit_cast(unsigned, f);
    unsigned r = u + 0x7FFFu + ((u >> 16) & 1u);   // RNE
    return (short)(r >> 16);
}
static __device__ __forceinline__ float bf2f(short h) {
    unsigned u = ((unsigned)(unsigned short)h) << 16;
    return __builtin_bit_cast(float, u);
}

__global__ __launch_bounds__(256, 2)
void sgcn_mfma(const float* __restrict__ x,
               const float* __restrict__ adj,
               const float* __restrict__ W,
               float* __restrict__ out)
{
    // hi/lo bf16 arrays; 6 x 9216 B = 55296 B LDS
    __shared__ short sXnH[ROWS][LDH], sXnL[ROWS][LDH];
    __shared__ short sKH [MT  ][LDH], sKL [MT  ][LDH];   // Xm tile [m][f]; reused for W in epilogue
    __shared__ short sPH [ROWS][LDH], sPL [ROWS][LDH];   // masked exp P [n][m]; reused for agg in epilogue

    const int wg = blockIdx.x;
    const int nb = wg & 7;
    const int bt = wg >> 3;
    const int t  = bt % TT;
    const int b  = bt / TT;
    const int n0 = nb * ROWS;

    const int tid  = threadIdx.x;
    const int w    = tid >> 6;        // wave 0..3, owns rows 16w..16w+15
    const int l    = tid & 63;
    const int lm   = l & 15;
    const int hi4  = l >> 4;
    const int koff = hi4 * 8;

    // ---- stage Xn (hi/lo) ----
    #pragma unroll
    for (int k = 0; k < 4; ++k) {
        int idx = tid + k * 256;
        int row = idx >> 4;
        int c4  = (idx & 15) << 2;
        v4f xv = *(const v4f*)(x + (((size_t)(b * NN + n0 + row) * TT + t) * FF) + c4);
        short4v h, lo;
        #pragma unroll
        for (int j = 0; j < 4; ++j) {
            short hh = f2bf(xv[j]);
            h[j]  = hh;
            lo[j] = f2bf(xv[j] - bf2f(hh));
        }
        *(short4v*)&sXnH[row][c4] = h;
        *(short4v*)&sXnL[row][c4] = lo;
    }

    f32x4 agg[4];
    #pragma unroll
    for (int c = 0; c < 4; ++c) { agg[c][0]=0.f; agg[c][1]=0.f; agg[c][2]=0.f; agg[c][3]=0.f; }
    float m_run[4], l_run[4], fac[4];
    #pragma unroll
    for (int r = 0; r < 4; ++r) { m_run[r] = -INFINITY; l_run[r] = 0.f; }

    const float* adjbase = adj + (size_t)(n0 + 16 * w + 4 * hi4) * NN + lm;

    for (int mt = 0; mt < NTILES; ++mt) {
        const int m0 = mt * MT;

        // ---- stage K tile (hi/lo), [m][f] ----
        #pragma unroll
        for (int k = 0; k < 4; ++k) {
            int idx = tid + k * 256;
            int row = idx >> 4;
            int c4  = (idx & 15) << 2;
            v4f xv = *(const v4f*)(x + (((size_t)(b * NN + m0 + row) * TT + t) * FF) + c4);
            short4v h, lo;
            #pragma unroll
            for (int j = 0; j < 4; ++j) {
                short hh = f2bf(xv[j]);
                h[j]  = hh;
                lo[j] = f2bf(xv[j] - bf2f(hh));
            }
            *(short4v*)&sKH[row][c4] = h;
            *(short4v*)&sKL[row][c4] = lo;
        }

        // prefetch adj for this tile (consumed after S MFMAs)
        float adjv[4][4];
        #pragma unroll
        for (int c = 0; c < 4; ++c)
            #pragma unroll
            for (int r = 0; r < 4; ++r)
                adjv[c][r] = adjbase[(size_t)r * NN + m0 + 16 * c];

        __syncthreads();

        // ---- S = Xn * Xm^T via 3-term hi/lo MFMA ----
        short8v aH[2], aL[2];
        #pragma unroll
        for (int ks = 0; ks < 2; ++ks) {
            aH[ks] = *(const short8v*)&sXnH[16 * w + lm][ks * 32 + koff];
            aL[ks] = *(const short8v*)&sXnL[16 * w + lm][ks * 32 + koff];
        }
        f32x4 sc[4];
        #pragma unroll
        for (int c = 0; c < 4; ++c) {
            f32x4 acc; acc[0]=0.f; acc[1]=0.f; acc[2]=0.f; acc[3]=0.f;
            #pragma unroll
            for (int ks = 0; ks < 2; ++ks) {
                short8v bH = *(const short8v*)&sKH[16 * c + lm][ks * 32 + koff];
                short8v bL = *(const short8v*)&sKL[16 * c + lm][ks * 32 + koff];
                acc = __builtin_amdgcn_mfma_f32_16x16x32_bf16(aH[ks], bH, acc, 0, 0, 0);
                acc = __builtin_amdgcn_mfma_f32_16x16x32_bf16(aH[ks], bL, acc, 0, 0, 0);
                acc = __builtin_amdgcn_mfma_f32_16x16x32_bf16(aL[ks], bH, acc, 0, 0, 0);
            }
            sc[c] = acc;
        }

        // ---- online softmax in C-fragment space (rows lane-local) ----
        #pragma unroll
        for (int r = 0; r < 4; ++r) {
            float mx = fmaxf(fmaxf(sc[0][r], sc[1][r]), fmaxf(sc[2][r], sc[3][r]));
            mx = fmaxf(mx, __shfl_xor(mx, 1));
            mx = fmaxf(mx, __shfl_xor(mx, 2));
            mx = fmaxf(mx, __shfl_xor(mx, 4));
            mx = fmaxf(mx, __shfl_xor(mx, 8));
            mx *= 0.125f;                      // logits are sc*0.125
            float mn = fmaxf(m_run[r], mx);
            fac[r] = __expf(m_run[r] - mn);    // 0 on first tile
            m_run[r] = mn;
            float ls = 0.f;
            #pragma unroll
            for (int c = 0; c < 4; ++c) {
                float e = __expf(sc[c][r] * 0.125f - mn);
                ls += e;                                   // denom WITHOUT adj
                float p = e * adjv[c][r];                  // post-softmax mask
                short ph = f2bf(p);
                sPH[16 * w + 4 * hi4 + r][16 * c + lm] = ph;
                sPL[16 * w + 4 * hi4 + r][16 * c + lm] = f2bf(p - bf2f(ph));
            }
            ls += __shfl_xor(ls, 1);
            ls += __shfl_xor(ls, 2);
            ls += __shfl_xor(ls, 4);
            ls += __shfl_xor(ls, 8);
            l_run[r] = l_run[r] * fac[r] + ls;
        }

        // ---- PV: agg += P * Xm (A from sP rows, B = Xm columns via u16 reads) ----
        short8v pH[2], pL[2];
        #pragma unroll
        for (int ks = 0; ks < 2; ++ks) {
            pH[ks] = *(const short8v*)&sPH[16 * w + lm][ks * 32 + koff];
            pL[ks] = *(const short8v*)&sPL[16 * w + lm][ks * 32 + koff];
        }
        #pragma unroll
        for (int c2 = 0; c2 < 4; ++c2) {
            #pragma unroll
            for (int r = 0; r < 4; ++r) agg[c2][r] *= fac[r];
            #pragma unroll
            for (int ks = 0; ks < 2; ++ks) {
                short8v bH, bL;
                #pragma unroll
                for (int j = 0; j < 8; ++j) {
                    bH[j] = sKH[ks * 32 + koff + j][16 * c2 + lm];
                    bL[j] = sKL[ks * 32 + koff + j][16 * c2 + lm];
                }
                agg[c2] = __builtin_amdgcn_mfma_f32_16x16x32_bf16(pH[ks], bH, agg[c2], 0, 0, 0);
                agg[c2] = __builtin_amdgcn_mfma_f32_16x16x32_bf16(pH[ks], bL, agg[c2], 0, 0, 0);
                agg[c2] = __builtin_amdgcn_mfma_f32_16x16x32_bf16(pL[ks], bH, agg[c2], 0, 0, 0);
            }
        }
        __syncthreads();   // protect sK before next stage
    }

    // ---- epilogue: normalize, out = relu(agg * W^T) via MFMA ----
    __syncthreads();       // all waves done with sK
    // stage W (hi/lo) into sK space
    #pragma unroll
    for (int k = 0; k < 4; ++k) {
        int idx = tid + k * 256;
        int row = idx >> 4;
        int c4  = (idx & 15) << 2;
        v4f wv = *(const v4f*)(W + row * FF + c4);
        short4v h, lo;
        #pragma unroll
        for (int j = 0; j < 4; ++j) {
            short hh = f2bf(wv[j]);
            h[j]  = hh;
            lo[j] = f2bf(wv[j] - bf2f(hh));
        }
        *(short4v*)&sKH[row][c4] = h;
        *(short4v*)&sKL[row][c4] = lo;
    }

    float nrm[4];
    #pragma unroll
    for (int r = 0; r < 4; ++r) nrm[r] = 0.125f / l_run[r];

    // write normalized agg (hi/lo) into sP rows (own wave region)
    #pragma unroll
    for (int c2 = 0; c2 < 4; ++c2)
        #pragma unroll
        for (int r = 0; r < 4; ++r) {
            float v = agg[c2][r] * nrm[r];
            short hh = f2bf(v);
            sPH[16 * w + 4 * hi4 + r][16 * c2 + lm] = hh;
            sPL[16 * w + 4 * hi4 + r][16 * c2 + lm] = f2bf(v - bf2f(hh));
        }
    __syncthreads();       // W staged

    short8v gH[2], gL[2];
    #pragma unroll
    for (int ks = 0; ks < 2; ++ks) {
        gH[ks] = *(const short8v*)&sPH[16 * w + lm][ks * 32 + koff];
        gL[ks] = *(const short8v*)&sPL[16 * w + lm][ks * 32 + koff];
    }

    float* obase = out + (((size_t)(b * NN + n0 + 16 * w + 4 * hi4) * TT + t) * FF) + lm;
    #pragma unroll
    for (int c2 = 0; c2 < 4; ++c2) {
        f32x4 acc; acc[0]=0.f; acc[1]=0.f; acc[2]=0.f; acc[3]=0.f;
        #pragma unroll
        for (int ks = 0; ks < 2; ++ks) {
            short8v bH = *(const short8v*)&sKH[16 * c2 + lm][ks * 32 + koff];
            short8v bL = *(const short8v*)&sKL[16 * c2 + lm][ks * 32 + koff];
            acc = __builtin_amdgcn_mfma_f32_16x16x32_bf16(gH[ks], bH, acc, 0, 0, 0);
            acc = __builtin_amdgcn_mfma_f32_16x16x32_bf16(gH[ks], bL, acc, 0, 0, 0);
            acc = __builtin_amdgcn_mfma_f32_16x16x32_bf16(gL[ks], bH, acc, 0, 0, 0);
        }
        #pragma unroll
        for (int r = 0; r < 4; ++r)
            obase[(size_t)r * TT * FF + 16 * c2] = fmaxf(acc[r], 0.f);
    }
}

extern "C" void kernel_launch(void* const* d_in, const int* in_sizes, int n_in,
                              void* d_out, int out_size, void* d_ws, size_t ws_size,
                              hipStream_t stream) {
    const float* x   = (const float*)d_in[0];
    const float* adj = (const float*)d_in[1];
    const float* W   = (const float*)d_in[2];
    float* out = (float*)d_out;

    dim3 grid(BB * TT * (NN / ROWS));   // 3072
    sgcn_mfma<<<grid, dim3(256), 0, stream>>>(x, adj, W, out);
}

// Round 3
// 187.987 us; speedup vs baseline: 2.2124x; 1.4779x over previous
//
#include <hip/hip_runtime.h>
#include <math.h>

// B,N,T,F = 32,512,12,64
#define BB 32
#define NN 512
#define TT 12
#define FF 64
#define ROWS 64            // query rows per WG
#define MT 64              // key tile
#define NTILES (NN / MT)
#define LDH 72             // row-major LDS stride (shorts): 144 B rows, 16B-aligned
#define LDT 68             // transposed LDS stride (shorts): 136 B rows, 8B-aligned

typedef float  f32x4   __attribute__((ext_vector_type(4)));
typedef float  v4f     __attribute__((ext_vector_type(4)));
typedef short  short8v __attribute__((ext_vector_type(8)));
typedef short  short4v __attribute__((ext_vector_type(4)));

static __device__ __forceinline__ short f2bf(float f) {
    unsigned u = __builtin_bit_cast(unsigned, f);
    unsigned r = u + 0x7FFFu + ((u >> 16) & 1u);   // RNE
    return (short)(r >> 16);
}
static __device__ __forceinline__ float bf2f(short h) {
    unsigned u = ((unsigned)(unsigned short)h) << 16;
    return __builtin_bit_cast(float, u);
}

__global__ __launch_bounds__(256, 3)
void sgcn_mfma2(const float* __restrict__ x,
                const float* __restrict__ adj,
                const float* __restrict__ W,
                float* __restrict__ out)
{
    // 18432 + 17408 + 9216 = 45056 B -> 3 blocks/CU
    __shared__ __align__(16) short sKH [MT][LDH], sKL [MT][LDH];  // K tile [m][f]; W in epilogue
    __shared__ __align__(16) short sKTH[FF][LDT], sKTL[FF][LDT];  // K tile transposed [f][m]; agg-lo in epilogue
    __shared__ __align__(16) short sPH [ROWS][LDH];               // masked exp P (hi only); agg-hi in epilogue

    const int wg = blockIdx.x;
    const int nb = wg & 7;
    const int bt = wg >> 3;
    const int t  = bt % TT;
    const int b  = bt / TT;
    const int n0 = nb * ROWS;

    const int tid  = threadIdx.x;
    const int w    = tid >> 6;        // wave 0..3, owns rows 16w..16w+15
    const int l    = tid & 63;
    const int lm   = l & 15;
    const int hi4  = l >> 4;
    const int koff = hi4 * 8;

    // ---- Xn A-fragments: once, directly from global (hi/lo in regs) ----
    short8v aH[2], aL[2];
    {
        const float* xrow = x + (((size_t)(b * NN + n0 + 16 * w + lm) * TT + t) * FF);
        #pragma unroll
        for (int ks = 0; ks < 2; ++ks) {
            f32x4 x0 = *(const f32x4*)(xrow + ks * 32 + koff);
            f32x4 x1 = *(const f32x4*)(xrow + ks * 32 + koff + 4);
            #pragma unroll
            for (int j = 0; j < 4; ++j) {
                short hh = f2bf(x0[j]);
                aH[ks][j] = hh;
                aL[ks][j] = f2bf(x0[j] - bf2f(hh));
            }
            #pragma unroll
            for (int j = 0; j < 4; ++j) {
                short hh = f2bf(x1[j]);
                aH[ks][4 + j] = hh;
                aL[ks][4 + j] = f2bf(x1[j] - bf2f(hh));
            }
        }
    }

    f32x4 agg[4];
    #pragma unroll
    for (int c = 0; c < 4; ++c) { agg[c][0]=0.f; agg[c][1]=0.f; agg[c][2]=0.f; agg[c][3]=0.f; }
    float m_run[4], l_run[4], fac[4];
    #pragma unroll
    for (int r = 0; r < 4; ++r) { m_run[r] = -INFINITY; l_run[r] = 0.f; }

    const float* adjbase = adj + (size_t)(n0 + 16 * w + 4 * hi4) * NN + lm;

    for (int mt = 0; mt < NTILES; ++mt) {
        const int m0 = mt * MT;

        // ---- stage K tile: row-major (hi/lo) + transposed (hi/lo) ----
        #pragma unroll
        for (int k = 0; k < 4; ++k) {
            int idx = tid + k * 256;
            int row = idx >> 4;
            int c4  = (idx & 15) << 2;
            v4f xv = *(const v4f*)(x + (((size_t)(b * NN + m0 + row) * TT + t) * FF) + c4);
            short4v h, lo;
            #pragma unroll
            for (int j = 0; j < 4; ++j) {
                short hh = f2bf(xv[j]);
                h[j]  = hh;
                lo[j] = f2bf(xv[j] - bf2f(hh));
            }
            *(short4v*)&sKH[row][c4] = h;
            *(short4v*)&sKL[row][c4] = lo;
            #pragma unroll
            for (int j = 0; j < 4; ++j) {
                sKTH[c4 + j][row] = h[j];
                sKTL[c4 + j][row] = lo[j];
            }
        }

        // prefetch adj for this tile
        float adjv[4][4];
        #pragma unroll
        for (int c = 0; c < 4; ++c)
            #pragma unroll
            for (int r = 0; r < 4; ++r)
                adjv[c][r] = adjbase[(size_t)r * NN + m0 + 16 * c];

        __syncthreads();

        // ---- S = Xn * Xm^T via 3-term hi/lo MFMA ----
        f32x4 sc[4];
        #pragma unroll
        for (int c = 0; c < 4; ++c) {
            f32x4 acc; acc[0]=0.f; acc[1]=0.f; acc[2]=0.f; acc[3]=0.f;
            #pragma unroll
            for (int ks = 0; ks < 2; ++ks) {
                short8v bH = *(const short8v*)&sKH[16 * c + lm][ks * 32 + koff];
                short8v bL = *(const short8v*)&sKL[16 * c + lm][ks * 32 + koff];
                acc = __builtin_amdgcn_mfma_f32_16x16x32_bf16(aH[ks], bH, acc, 0, 0, 0);
                acc = __builtin_amdgcn_mfma_f32_16x16x32_bf16(aH[ks], bL, acc, 0, 0, 0);
                acc = __builtin_amdgcn_mfma_f32_16x16x32_bf16(aL[ks], bH, acc, 0, 0, 0);
            }
            sc[c] = acc;
        }

        // ---- online softmax in C-fragment space (rows lane-local) ----
        #pragma unroll
        for (int r = 0; r < 4; ++r) {
            float mx = fmaxf(fmaxf(sc[0][r], sc[1][r]), fmaxf(sc[2][r], sc[3][r]));
            mx = fmaxf(mx, __shfl_xor(mx, 1));
            mx = fmaxf(mx, __shfl_xor(mx, 2));
            mx = fmaxf(mx, __shfl_xor(mx, 4));
            mx = fmaxf(mx, __shfl_xor(mx, 8));
            mx *= 0.125f;
            float mn = fmaxf(m_run[r], mx);
            fac[r] = __expf(m_run[r] - mn);    // 0 on first tile
            m_run[r] = mn;
            float ls = 0.f;
            #pragma unroll
            for (int c = 0; c < 4; ++c) {
                float e = __expf(sc[c][r] * 0.125f - mn);
                ls += e;                                   // denom WITHOUT adj
                float p = e * adjv[c][r];                  // post-softmax mask
                sPH[16 * w + 4 * hi4 + r][16 * c + lm] = f2bf(p);
            }
            ls += __shfl_xor(ls, 1);
            ls += __shfl_xor(ls, 2);
            ls += __shfl_xor(ls, 4);
            ls += __shfl_xor(ls, 8);
            l_run[r] = l_run[r] * fac[r] + ls;
        }

        // ---- PV: agg += P * Xm (B-fragments from transposed K tile) ----
        short8v pH[2];
        #pragma unroll
        for (int ks = 0; ks < 2; ++ks)
            pH[ks] = *(const short8v*)&sPH[16 * w + lm][ks * 32 + koff];

        #pragma unroll
        for (int c2 = 0; c2 < 4; ++c2) {
            #pragma unroll
            for (int r = 0; r < 4; ++r) agg[c2][r] *= fac[r];
            #pragma unroll
            for (int ks = 0; ks < 2; ++ks) {
                short4v h0 = *(const short4v*)&sKTH[16 * c2 + lm][ks * 32 + koff];
                short4v h1 = *(const short4v*)&sKTH[16 * c2 + lm][ks * 32 + koff + 4];
                short4v l0 = *(const short4v*)&sKTL[16 * c2 + lm][ks * 32 + koff];
                short4v l1 = *(const short4v*)&sKTL[16 * c2 + lm][ks * 32 + koff + 4];
                short8v bH = __builtin_shufflevector(h0, h1, 0,1,2,3,4,5,6,7);
                short8v bL = __builtin_shufflevector(l0, l1, 0,1,2,3,4,5,6,7);
                agg[c2] = __builtin_amdgcn_mfma_f32_16x16x32_bf16(pH[ks], bH, agg[c2], 0, 0, 0);
                agg[c2] = __builtin_amdgcn_mfma_f32_16x16x32_bf16(pH[ks], bL, agg[c2], 0, 0, 0);
            }
        }
        __syncthreads();   // protect sK/sKT/sP before next stage
    }

    // ---- epilogue: normalize, out = relu(agg * W^T) via MFMA ----
    // stage W (hi/lo) into sKH/sKL
    #pragma unroll
    for (int k = 0; k < 4; ++k) {
        int idx = tid + k * 256;
        int row = idx >> 4;
        int c4  = (idx & 15) << 2;
        v4f wv = *(const v4f*)(W + row * FF + c4);
        short4v h, lo;
        #pragma unroll
        for (int j = 0; j < 4; ++j) {
            short hh = f2bf(wv[j]);
            h[j]  = hh;
            lo[j] = f2bf(wv[j] - bf2f(hh));
        }
        *(short4v*)&sKH[row][c4] = h;
        *(short4v*)&sKL[row][c4] = lo;
    }

    float nrm[4];
    #pragma unroll
    for (int r = 0; r < 4; ++r) nrm[r] = 0.125f / l_run[r];

    // normalized agg: hi into sPH, lo into sKTH (both own-wave regions)
    #pragma unroll
    for (int c2 = 0; c2 < 4; ++c2)
        #pragma unroll
        for (int r = 0; r < 4; ++r) {
            float v = agg[c2][r] * nrm[r];
            short hh = f2bf(v);
            sPH [16 * w + 4 * hi4 + r][16 * c2 + lm] = hh;
            sKTH[16 * w + 4 * hi4 + r][16 * c2 + lm] = f2bf(v - bf2f(hh));
        }
    __syncthreads();       // W staged, agg fragments visible

    short8v gH[2], gL[2];
    #pragma unroll
    for (int ks = 0; ks < 2; ++ks) {
        gH[ks] = *(const short8v*)&sPH[16 * w + lm][ks * 32 + koff];
        short4v g0 = *(const short4v*)&sKTH[16 * w + lm][ks * 32 + koff];
        short4v g1 = *(const short4v*)&sKTH[16 * w + lm][ks * 32 + koff + 4];
        gL[ks] = __builtin_shufflevector(g0, g1, 0,1,2,3,4,5,6,7);
    }

    float* obase = out + (((size_t)(b * NN + n0 + 16 * w + 4 * hi4) * TT + t) * FF) + lm;
    #pragma unroll
    for (int c2 = 0; c2 < 4; ++c2) {
        f32x4 acc; acc[0]=0.f; acc[1]=0.f; acc[2]=0.f; acc[3]=0.f;
        #pragma unroll
        for (int ks = 0; ks < 2; ++ks) {
            short8v bH = *(const short8v*)&sKH[16 * c2 + lm][ks * 32 + koff];
            short8v bL = *(const short8v*)&sKL[16 * c2 + lm][ks * 32 + koff];
            acc = __builtin_amdgcn_mfma_f32_16x16x32_bf16(gH[ks], bH, acc, 0, 0, 0);
            acc = __builtin_amdgcn_mfma_f32_16x16x32_bf16(gH[ks], bL, acc, 0, 0, 0);
            acc = __builtin_amdgcn_mfma_f32_16x16x32_bf16(gL[ks], bH, acc, 0, 0, 0);
        }
        #pragma unroll
        for (int r = 0; r < 4; ++r)
            obase[(size_t)r * TT * FF + 16 * c2] = fmaxf(acc[r], 0.f);
    }
}

extern "C" void kernel_launch(void* const* d_in, const int* in_sizes, int n_in,
                              void* d_out, int out_size, void* d_ws, size_t ws_size,
                              hipStream_t stream) {
    const float* x   = (const float*)d_in[0];
    const float* adj = (const float*)d_in[1];
    const float* W   = (const float*)d_in[2];
    float* out = (float*)d_out;

    dim3 grid(BB * TT * (NN / ROWS));   // 3072
    sgcn_mfma2<<<grid, dim3(256), 0, stream>>>(x, adj, W, out);
}